// Round 2
// baseline (363.005 us; speedup 1.0000x reference)
//
#include <hip/hip_runtime.h>
#include <hip/hip_bf16.h>
#include <stdint.h>
#include <stddef.h>

#define DIM 1024
#define SEQ 2048
#define KF 24

using f32x4  = __attribute__((ext_vector_type(4))) float;
using bf16x8 = __attribute__((ext_vector_type(8))) short;

__device__ __forceinline__ float bf2f(unsigned short u){
  union { unsigned int i; float f; } v; v.i = ((unsigned int)u) << 16; return v.f;
}
__device__ __forceinline__ unsigned short f2bf(float f){
  union { float f; unsigned int i; } v; v.f = f;
  unsigned int r = v.i + 0x7FFFu + ((v.i >> 16) & 1u);  // RNE
  return (unsigned short)(r >> 16);
}
__device__ __forceinline__ void gload_lds16(const void* g, void* l){
  __builtin_amdgcn_global_load_lds(
      (const __attribute__((address_space(1))) unsigned int*)g,
      (__attribute__((address_space(3))) unsigned int*)l, 16, 0, 0);
}

// ---------------- prep: x fp32 -> bf16 ----------------
__global__ void k_cvt_x(const float* __restrict__ x, unsigned short* __restrict__ xb){
  int i = blockIdx.x * 256 + threadIdx.x;            // each thread 4 elems
  const float4* x4 = (const float4*)x;
  float4 v = x4[i];
  ushort4 o;
  o.x = f2bf(v.x); o.y = f2bf(v.y); o.z = f2bf(v.z); o.w = f2bf(v.w);
  *(ushort4*)(xb + (size_t)i * 4) = o;
}

// ---------------- prep: M_inputs transpose -> bf16 (B^T, [d][e]) ----------------
__global__ void k_tr_M(const float* __restrict__ Mi, unsigned short* __restrict__ MbT){
  __shared__ float tile[32][33];
  int e0 = blockIdx.y * 32, d0 = blockIdx.x * 32;
  int tx = threadIdx.x, ty = threadIdx.y;            // block (32,8)
  #pragma unroll
  for (int r = 0; r < 32; r += 8)
    tile[ty + r][tx] = Mi[(size_t)(e0 + ty + r) * DIM + d0 + tx];
  __syncthreads();
  #pragma unroll
  for (int r = 0; r < 32; r += 8)
    MbT[(size_t)(d0 + ty + r) * DIM + e0 + tx] = f2bf(tile[tx][ty + r]);
}

// ---------------- prep: pe[r][d] = 2 * (filters @ M_filters)[2r][d], bf16 ----------------
__global__ void k_pe(const float* __restrict__ filters, const float* __restrict__ Mf,
                     unsigned short* __restrict__ pe){
  int d = blockIdx.x * 256 + threadIdx.x;            // 0..1023
  int r = blockIdx.y;                                // 0..1023
  float acc = 0.f;
  #pragma unroll
  for (int k = 0; k < KF; ++k)
    acc += filters[(size_t)(2 * r) * KF + k] * Mf[(size_t)k * DIM + d];
  pe[(size_t)r * DIM + d] = f2bf(2.f * acc);
}

// ---------------- GEMM: x_proj = x @ M_inputs (bf16 MFMA, bf16 out) ----------------
#define BM 128
#define BN 128
#define BKK 64
__global__ void k_gemm(const unsigned short* __restrict__ A,
                       const unsigned short* __restrict__ Bt,
                       unsigned short* __restrict__ C){
  __shared__ unsigned short As[BM * BKK];   // 16 KB, XOR-swizzled (unit16B ^= row&7)
  __shared__ unsigned short Bs[BN * BKK];   // 16 KB
  int tid  = threadIdx.x;
  int lane = tid & 63, wave = tid >> 6;
  int wm = wave >> 1, wn = wave & 1;
  int trow0 = blockIdx.x * BM;
  int ncol0 = blockIdx.y * BN;

  f32x4 acc[4][4] = {};

  for (int kt = 0; kt < 1024 / BKK; ++kt){
    __syncthreads();
    #pragma unroll
    for (int g = 0; g < 4; ++g){
      int c  = wave * 4 + g;              // chunk 0..15, 1KB each
      int mr = c * 8 + (lane >> 3);       // tile row this lane stages
      int u  = lane & 7;                  // physical 16B unit within row
      int su = u ^ (mr & 7);              // source (logical) unit
      const unsigned short* srcA = A + (size_t)(trow0 + mr) * 1024 + kt * BKK + su * 8;
      gload_lds16(srcA, (char*)As + c * 1024);
      const unsigned short* srcB = Bt + (size_t)(ncol0 + mr) * 1024 + kt * BKK + su * 8;
      gload_lds16(srcB, (char*)Bs + c * 1024);
    }
    __syncthreads();

    bf16x8 af[4][2], bfr[4][2];
    #pragma unroll
    for (int mi = 0; mi < 4; ++mi){
      int row = wm * 64 + mi * 16 + (lane & 15);
      #pragma unroll
      for (int ks = 0; ks < 2; ++ks){
        int u = ((lane >> 4) + 4 * ks) ^ (row & 7);
        af[mi][ks] = *(const bf16x8*)((const char*)As + row * 128 + u * 16);
      }
    }
    #pragma unroll
    for (int ni = 0; ni < 4; ++ni){
      int row = wn * 64 + ni * 16 + (lane & 15);
      #pragma unroll
      for (int ks = 0; ks < 2; ++ks){
        int u = ((lane >> 4) + 4 * ks) ^ (row & 7);
        bfr[ni][ks] = *(const bf16x8*)((const char*)Bs + row * 128 + u * 16);
      }
    }
    #pragma unroll
    for (int mi = 0; mi < 4; ++mi)
      #pragma unroll
      for (int ni = 0; ni < 4; ++ni)
        #pragma unroll
        for (int ks = 0; ks < 2; ++ks)
          acc[mi][ni] = __builtin_amdgcn_mfma_f32_16x16x32_bf16(
              af[mi][ks], bfr[ni][ks], acc[mi][ni], 0, 0, 0);
  }

  #pragma unroll
  for (int mi = 0; mi < 4; ++mi)
    #pragma unroll
    for (int ni = 0; ni < 4; ++ni){
      int col = ncol0 + wn * 64 + ni * 16 + (lane & 15);
      #pragma unroll
      for (int reg = 0; reg < 4; ++reg){
        int row = trow0 + wm * 64 + mi * 16 + (lane >> 4) * 4 + reg;
        C[(size_t)row * 1024 + col] = f2bf(acc[mi][ni][reg]);
      }
    }
}

// ---------------- depthwise causal conv (half-rate, even-lag filter) ----------------
// out[m] = sum_{r<=m} pe[r]*x[m-r], per (b,p,d) column; m-tile of 32 per call.
// Chunks over r, descending r0 = m0+16, m0, ..., 0. Sliding 48-reg x window,
// next-chunk x/pe prefetched into regs so loads overlap the 512-FMA block.
#define MV 32
__device__ __forceinline__ void conv_tile(const unsigned short* __restrict__ xcol,
                                          const unsigned short* __restrict__ pcol,
                                          float* __restrict__ ocol, int m0){
  float acc[MV];
  #pragma unroll
  for (int m = 0; m < MV; ++m) acc[m] = 0.f;

  float xw[48];                       // x[jbase .. jbase+47], jbase = 16*ch - 31
  #pragma unroll
  for (int i = 0; i < 31; ++i) xw[i] = 0.f;
  #pragma unroll
  for (int i = 0; i < 17; ++i) xw[31 + i] = bf2f(xcol[(size_t)i * 2048]);

  float pv[16];                       // pe[r0 .. r0+15], r0 = m0+16-16*ch
  #pragma unroll
  for (int i = 0; i < 16; ++i) pv[i] = bf2f(pcol[(size_t)(m0 + 16 + i) * 1024]);

  int nch = (m0 >> 4) + 2;
  for (int ch = 0; ch < nch - 1; ++ch){
    // prefetch chunk ch+1: 16 new x (j = 16ch+17 .. 16ch+32) and 16 pe rows
    float nx[16], npv[16];
    #pragma unroll
    for (int i = 0; i < 16; ++i){
      int j = 16 * ch + 17 + i;
      nx[i] = (j < 1024) ? bf2f(xcol[(size_t)j * 2048]) : 0.f;
    }
    #pragma unroll
    for (int i = 0; i < 16; ++i)
      npv[i] = bf2f(pcol[(size_t)(m0 - 16 * ch + i) * 1024]);

    #pragma unroll
    for (int i = 0; i < 16; ++i)
      #pragma unroll
      for (int m = 0; m < MV; ++m)
        acc[m] += pv[i] * xw[m + 15 - i];

    #pragma unroll
    for (int i = 0; i < 32; ++i) xw[i] = xw[i + 16];
    #pragma unroll
    for (int i = 0; i < 16; ++i) xw[32 + i] = nx[i];
    #pragma unroll
    for (int i = 0; i < 16; ++i) pv[i] = npv[i];
  }
  // last chunk (r0 = 0)
  #pragma unroll
  for (int i = 0; i < 16; ++i)
    #pragma unroll
    for (int m = 0; m < MV; ++m)
      acc[m] += pv[i] * xw[m + 15 - i];

  #pragma unroll
  for (int m = 0; m < MV; ++m)
    ocol[(size_t)(m0 + m) * 2048] = acc[m];
}

__global__ __launch_bounds__(256, 2)
void k_conv(const unsigned short* __restrict__ xp,   // [8192][1024] bf16
            const unsigned short* __restrict__ pe,   // [1024][1024] bf16
            float* __restrict__ out){                // [4][2048][1024] f32
  int d    = blockIdx.x * 256 + threadIdx.x;  // 0..1023
  int pair = blockIdx.y;                      // 0..15 -> tiles {pair, 31-pair}
  int bp   = blockIdx.z;                      // 0..7
  int b = bp >> 1, p = bp & 1;
  const unsigned short* xcol = xp + (size_t)(b * SEQ + p) * DIM + d;
  const unsigned short* pcol = pe + d;
  float* ocol = out + (size_t)(b * SEQ + p) * DIM + d;

  conv_tile(xcol, pcol, ocol, pair * MV);          // small tile
  conv_tile(xcol, pcol, ocol, (31 - pair) * MV);   // large tile (balanced: 66 chunks total)
}

extern "C" void kernel_launch(void* const* d_in, const int* in_sizes, int n_in,
                              void* d_out, int out_size, void* d_ws, size_t ws_size,
                              hipStream_t stream){
  const float* x       = (const float*)d_in[0];
  const float* filters = (const float*)d_in[1];
  const float* Mi      = (const float*)d_in[2];
  const float* Mf      = (const float*)d_in[3];

  char* ws = (char*)d_ws;
  unsigned short* Xb  = (unsigned short*)(ws);                              // 16 MB
  unsigned short* XPb = (unsigned short*)(ws + (size_t)16 * 1024 * 1024);   // 16 MB
  unsigned short* MbT = (unsigned short*)(ws + (size_t)32 * 1024 * 1024);   //  2 MB
  unsigned short* pe  = (unsigned short*)(ws + (size_t)34 * 1024 * 1024);   //  2 MB
  float* out = (float*)d_out;

  hipLaunchKernelGGL(k_cvt_x, dim3(8192), dim3(256), 0, stream, x, Xb);
  hipLaunchKernelGGL(k_tr_M,  dim3(32, 32), dim3(32, 8), 0, stream, Mi, MbT);
  hipLaunchKernelGGL(k_pe,    dim3(4, 1024), dim3(256), 0, stream, filters, Mf, pe);
  hipLaunchKernelGGL(k_gemm,  dim3(64, 8), dim3(256), 0, stream, Xb, MbT, XPb);
  hipLaunchKernelGGL(k_conv,  dim3(4, 16, 8), dim3(256), 0, stream, XPb, pe, out);
}

// Round 3
// 189.684 us; speedup vs baseline: 1.9137x; 1.9137x over previous
//
#include <hip/hip_runtime.h>
#include <hip/hip_bf16.h>
#include <stdint.h>
#include <stddef.h>

#define DIM 1024
#define SEQ 2048
#define KF 24

using f32x4  = __attribute__((ext_vector_type(4))) float;
using bf16x8 = __attribute__((ext_vector_type(8))) short;

__device__ __forceinline__ float bf2f(unsigned short u){
  union { unsigned int i; float f; } v; v.i = ((unsigned int)u) << 16; return v.f;
}
__device__ __forceinline__ unsigned short f2bf(float f){
  union { float f; unsigned int i; } v; v.f = f;
  unsigned int r = v.i + 0x7FFFu + ((v.i >> 16) & 1u);  // RNE
  return (unsigned short)(r >> 16);
}
__device__ __forceinline__ void gload_lds16(const void* g, void* l){
  __builtin_amdgcn_global_load_lds(
      (const __attribute__((address_space(1))) unsigned int*)g,
      (__attribute__((address_space(3))) unsigned int*)l, 16, 0, 0);
}

// ---------------- prep: x fp32 -> bf16 ----------------
__global__ void k_cvt_x(const float* __restrict__ x, unsigned short* __restrict__ xb){
  int i = blockIdx.x * 256 + threadIdx.x;            // each thread 4 elems
  const float4* x4 = (const float4*)x;
  float4 v = x4[i];
  ushort4 o;
  o.x = f2bf(v.x); o.y = f2bf(v.y); o.z = f2bf(v.z); o.w = f2bf(v.w);
  *(ushort4*)(xb + (size_t)i * 4) = o;
}

// ---------------- prep: M_inputs transpose -> bf16 (B^T, [d][e]) ----------------
__global__ void k_tr_M(const float* __restrict__ Mi, unsigned short* __restrict__ MbT){
  __shared__ float tile[32][33];
  int e0 = blockIdx.y * 32, d0 = blockIdx.x * 32;
  int tx = threadIdx.x, ty = threadIdx.y;            // block (32,8)
  #pragma unroll
  for (int r = 0; r < 32; r += 8)
    tile[ty + r][tx] = Mi[(size_t)(e0 + ty + r) * DIM + d0 + tx];
  __syncthreads();
  #pragma unroll
  for (int r = 0; r < 32; r += 8)
    MbT[(size_t)(d0 + ty + r) * DIM + e0 + tx] = f2bf(tile[tx][ty + r]);
}

// ---------------- prep: pe[r][d] = 2 * (filters @ M_filters)[2r][d], bf16 ----------------
__global__ void k_pe(const float* __restrict__ filters, const float* __restrict__ Mf,
                     unsigned short* __restrict__ pe){
  int d = blockIdx.x * 256 + threadIdx.x;            // 0..1023
  int r = blockIdx.y;                                // 0..1023
  float acc = 0.f;
  #pragma unroll
  for (int k = 0; k < KF; ++k)
    acc += filters[(size_t)(2 * r) * KF + k] * Mf[(size_t)k * DIM + d];
  pe[(size_t)r * DIM + d] = f2bf(2.f * acc);
}

// ---------------- GEMM: x_proj = x @ M_inputs (bf16 MFMA, bf16 out) ----------------
#define BM 128
#define BN 128
#define BKK 64
__global__ void k_gemm(const unsigned short* __restrict__ A,
                       const unsigned short* __restrict__ Bt,
                       unsigned short* __restrict__ C){
  __shared__ unsigned short As[BM * BKK];   // 16 KB, XOR-swizzled (unit16B ^= row&7)
  __shared__ unsigned short Bs[BN * BKK];   // 16 KB
  int tid  = threadIdx.x;
  int lane = tid & 63, wave = tid >> 6;
  int wm = wave >> 1, wn = wave & 1;
  int trow0 = blockIdx.x * BM;
  int ncol0 = blockIdx.y * BN;

  f32x4 acc[4][4] = {};

  for (int kt = 0; kt < 1024 / BKK; ++kt){
    __syncthreads();
    #pragma unroll
    for (int g = 0; g < 4; ++g){
      int c  = wave * 4 + g;              // chunk 0..15, 1KB each
      int mr = c * 8 + (lane >> 3);       // tile row this lane stages
      int u  = lane & 7;                  // physical 16B unit within row
      int su = u ^ (mr & 7);              // source (logical) unit
      const unsigned short* srcA = A + (size_t)(trow0 + mr) * 1024 + kt * BKK + su * 8;
      gload_lds16(srcA, (char*)As + c * 1024);
      const unsigned short* srcB = Bt + (size_t)(ncol0 + mr) * 1024 + kt * BKK + su * 8;
      gload_lds16(srcB, (char*)Bs + c * 1024);
    }
    __syncthreads();

    bf16x8 af[4][2], bfr[4][2];
    #pragma unroll
    for (int mi = 0; mi < 4; ++mi){
      int row = wm * 64 + mi * 16 + (lane & 15);
      #pragma unroll
      for (int ks = 0; ks < 2; ++ks){
        int u = ((lane >> 4) + 4 * ks) ^ (row & 7);
        af[mi][ks] = *(const bf16x8*)((const char*)As + row * 128 + u * 16);
      }
    }
    #pragma unroll
    for (int ni = 0; ni < 4; ++ni){
      int row = wn * 64 + ni * 16 + (lane & 15);
      #pragma unroll
      for (int ks = 0; ks < 2; ++ks){
        int u = ((lane >> 4) + 4 * ks) ^ (row & 7);
        bfr[ni][ks] = *(const bf16x8*)((const char*)Bs + row * 128 + u * 16);
      }
    }
    #pragma unroll
    for (int mi = 0; mi < 4; ++mi)
      #pragma unroll
      for (int ni = 0; ni < 4; ++ni)
        #pragma unroll
        for (int ks = 0; ks < 2; ++ks)
          acc[mi][ni] = __builtin_amdgcn_mfma_f32_16x16x32_bf16(
              af[mi][ks], bfr[ni][ks], acc[mi][ni], 0, 0, 0);
  }

  #pragma unroll
  for (int mi = 0; mi < 4; ++mi)
    #pragma unroll
    for (int ni = 0; ni < 4; ++ni){
      int col = ncol0 + wn * 64 + ni * 16 + (lane & 15);
      #pragma unroll
      for (int reg = 0; reg < 4; ++reg){
        int row = trow0 + wm * 64 + mi * 16 + (lane >> 4) * 4 + reg;
        C[(size_t)row * 1024 + col] = f2bf(acc[mi][ni][reg]);
      }
    }
}

// ---------------- depthwise causal conv (half-rate, even-lag filter) ----------------
// out[m] = sum_{r<=m} pe[r]*x[m-r] per (b,p,d) column. MV=16 outputs/thread.
// Chunks of 16 taps, r0 descending m0,m0-16,...,0. 31-reg sliding x window,
// 16 x + 16 pe prefetched into regs for the next chunk (fits 128-VGPR budget
// at 4 waves/SIMD so loads stay in flight under the FMA block).
#define MV 16
__device__ __forceinline__ void conv_tile16(const unsigned short* __restrict__ xcol,
                                            const unsigned short* __restrict__ pcol,
                                            float* __restrict__ ocol, int m0){
  float acc[MV];
  #pragma unroll
  for (int m = 0; m < MV; ++m) acc[m] = 0.f;

  // window xw[t] = x[j0+t], j0 = m0-r0-15; chunk 0 has r0=m0 -> j0=-15
  float xw[31];
  #pragma unroll
  for (int t = 0; t < 15; ++t) xw[t] = 0.f;
  #pragma unroll
  for (int t = 0; t < 16; ++t) xw[15 + t] = bf2f(xcol[(size_t)t * 2048]);

  float pv[16];
  #pragma unroll
  for (int i = 0; i < 16; ++i) pv[i] = bf2f(pcol[(size_t)(m0 + i) * 1024]);

  int nch = (m0 >> 4) + 1;
  int r0 = m0;
  for (int c = 0; c < nch - 1; ++c){
    // prefetch chunk c+1: fresh x at j = m0-r0+16+i (proven <= 1023), pe[r0-16+i]
    float nx[16], npv[16];
    int xb = m0 - r0 + 16;
    #pragma unroll
    for (int i = 0; i < 16; ++i) nx[i]  = bf2f(xcol[(size_t)(xb + i) * 2048]);
    #pragma unroll
    for (int i = 0; i < 16; ++i) npv[i] = bf2f(pcol[(size_t)(r0 - 16 + i) * 1024]);

    #pragma unroll
    for (int i = 0; i < 16; ++i)
      #pragma unroll
      for (int m = 0; m < MV; ++m)
        acc[m] += pv[i] * xw[m + 15 - i];

    #pragma unroll
    for (int t = 0; t < 15; ++t) xw[t] = xw[t + 16];
    #pragma unroll
    for (int t = 0; t < 16; ++t) xw[15 + t] = nx[t];
    #pragma unroll
    for (int i = 0; i < 16; ++i) pv[i] = npv[i];
    r0 -= 16;
  }
  // last chunk (r0 == 0)
  #pragma unroll
  for (int i = 0; i < 16; ++i)
    #pragma unroll
    for (int m = 0; m < MV; ++m)
      acc[m] += pv[i] * xw[m + 15 - i];

  #pragma unroll
  for (int m = 0; m < MV; ++m)
    ocol[(size_t)(m0 + m) * 2048] = acc[m];
}

__global__ __launch_bounds__(256, 4)
void k_conv(const unsigned short* __restrict__ xp,   // [8192][1024] bf16
            const unsigned short* __restrict__ pe,   // [1024][1024] bf16
            float* __restrict__ out){                // [4][2048][1024] f32
  int d    = blockIdx.x * 256 + threadIdx.x;  // 0..1023
  int pair = blockIdx.y;                      // 0..31 -> tiles {pair, 63-pair}
  int bp   = blockIdx.z;                      // 0..7
  int b = bp >> 1, p = bp & 1;
  const unsigned short* xcol = xp + (size_t)(b * SEQ + p) * DIM + d;
  const unsigned short* pcol = pe + d;
  float* ocol = out + (size_t)(b * SEQ + p) * DIM + d;

  conv_tile16(xcol, pcol, ocol, pair * MV);          // small tile
  conv_tile16(xcol, pcol, ocol, (63 - pair) * MV);   // large tile (65 chunks total)
}

extern "C" void kernel_launch(void* const* d_in, const int* in_sizes, int n_in,
                              void* d_out, int out_size, void* d_ws, size_t ws_size,
                              hipStream_t stream){
  const float* x       = (const float*)d_in[0];
  const float* filters = (const float*)d_in[1];
  const float* Mi      = (const float*)d_in[2];
  const float* Mf      = (const float*)d_in[3];

  char* ws = (char*)d_ws;
  unsigned short* Xb  = (unsigned short*)(ws);                              // 16 MB
  unsigned short* XPb = (unsigned short*)(ws + (size_t)16 * 1024 * 1024);   // 16 MB
  unsigned short* MbT = (unsigned short*)(ws + (size_t)32 * 1024 * 1024);   //  2 MB
  unsigned short* pe  = (unsigned short*)(ws + (size_t)34 * 1024 * 1024);   //  2 MB
  float* out = (float*)d_out;

  hipLaunchKernelGGL(k_cvt_x, dim3(8192), dim3(256), 0, stream, x, Xb);
  hipLaunchKernelGGL(k_tr_M,  dim3(32, 32), dim3(32, 8), 0, stream, Mi, MbT);
  hipLaunchKernelGGL(k_pe,    dim3(4, 1024), dim3(256), 0, stream, filters, Mf, pe);
  hipLaunchKernelGGL(k_gemm,  dim3(64, 8), dim3(256), 0, stream, Xb, MbT, XPb);
  hipLaunchKernelGGL(k_conv,  dim3(4, 32, 8), dim3(256), 0, stream, XPb, pe, out);
}

// Round 4
// 149.768 us; speedup vs baseline: 2.4238x; 1.2665x over previous
//
#include <hip/hip_runtime.h>
#include <hip/hip_bf16.h>
#include <stdint.h>
#include <stddef.h>

#define DIM 1024
#define SEQ 2048
#define KF 24

using f32x4  = __attribute__((ext_vector_type(4))) float;
using bf16x8 = __attribute__((ext_vector_type(8))) short;

__device__ __forceinline__ float bf2f(unsigned short u){
  union { unsigned int i; float f; } v; v.i = ((unsigned int)u) << 16; return v.f;
}
__device__ __forceinline__ unsigned short f2bf(float f){
  union { float f; unsigned int i; } v; v.f = f;
  unsigned int r = v.i + 0x7FFFu + ((v.i >> 16) & 1u);  // RNE
  return (unsigned short)(r >> 16);
}
// D = a.bf16[0]*b.bf16[0] + a.bf16[1]*b.bf16[1] + c   (V_DOT2_F32_BF16, VOP3P)
__device__ __forceinline__ float dot2bf(unsigned int a, unsigned int b, float c){
  float d;
  asm("v_dot2_f32_bf16 %0, %1, %2, %3" : "=v"(d) : "v"(a), "v"(b), "v"(c));
  return d;
}
__device__ __forceinline__ void gload_lds16(const void* g, void* l){
  __builtin_amdgcn_global_load_lds(
      (const __attribute__((address_space(1))) unsigned int*)g,
      (__attribute__((address_space(3))) unsigned int*)l, 16, 0, 0);
}

// ---------------- prep: x fp32 -> bf16 ----------------
__global__ void k_cvt_x(const float* __restrict__ x, unsigned short* __restrict__ xb){
  int i = blockIdx.x * 256 + threadIdx.x;            // each thread 4 elems
  const float4* x4 = (const float4*)x;
  float4 v = x4[i];
  ushort4 o;
  o.x = f2bf(v.x); o.y = f2bf(v.y); o.z = f2bf(v.z); o.w = f2bf(v.w);
  *(ushort4*)(xb + (size_t)i * 4) = o;
}

// ---------------- prep: M_inputs transpose -> bf16 (B^T, [d][e]) ----------------
__global__ void k_tr_M(const float* __restrict__ Mi, unsigned short* __restrict__ MbT){
  __shared__ float tile[32][33];
  int e0 = blockIdx.y * 32, d0 = blockIdx.x * 32;
  int tx = threadIdx.x, ty = threadIdx.y;            // block (32,8)
  #pragma unroll
  for (int r = 0; r < 32; r += 8)
    tile[ty + r][tx] = Mi[(size_t)(e0 + ty + r) * DIM + d0 + tx];
  __syncthreads();
  #pragma unroll
  for (int r = 0; r < 32; r += 8)
    MbT[(size_t)(d0 + ty + r) * DIM + e0 + tx] = f2bf(tile[tx][ty + r]);
}

// ---------------- prep: pe packed pairs ----------------
// pepk[r2][d] = u32{ lo = 2*phi[4*r2][d], hi = 2*phi[4*r2+2][d] }  (taps 2*r2, 2*r2+1)
__global__ void k_pe(const float* __restrict__ filters, const float* __restrict__ Mf,
                     unsigned int* __restrict__ pepk){
  int d  = blockIdx.x * 256 + threadIdx.x;           // 0..1023
  int r2 = blockIdx.y;                               // 0..511
  float a0 = 0.f, a1 = 0.f;
  #pragma unroll
  for (int k = 0; k < KF; ++k){
    float mf = Mf[(size_t)k * DIM + d];
    a0 += filters[(size_t)(4 * r2)     * KF + k] * mf;
    a1 += filters[(size_t)(4 * r2 + 2) * KF + k] * mf;
  }
  unsigned int lo = f2bf(2.f * a0), hi = f2bf(2.f * a1);
  pepk[(size_t)r2 * DIM + d] = lo | (hi << 16);
}

// ---------------- GEMM: x_proj = x @ M_inputs (bf16 MFMA, bf16 out) ----------------
#define BM 128
#define BN 128
#define BKK 64
__global__ void k_gemm(const unsigned short* __restrict__ A,
                       const unsigned short* __restrict__ Bt,
                       unsigned short* __restrict__ C){
  __shared__ unsigned short As[BM * BKK];   // 16 KB, XOR-swizzled (unit16B ^= row&7)
  __shared__ unsigned short Bs[BN * BKK];   // 16 KB
  int tid  = threadIdx.x;
  int lane = tid & 63, wave = tid >> 6;
  int wm = wave >> 1, wn = wave & 1;
  int trow0 = blockIdx.x * BM;
  int ncol0 = blockIdx.y * BN;

  f32x4 acc[4][4] = {};

  for (int kt = 0; kt < 1024 / BKK; ++kt){
    __syncthreads();
    #pragma unroll
    for (int g = 0; g < 4; ++g){
      int c  = wave * 4 + g;              // chunk 0..15, 1KB each
      int mr = c * 8 + (lane >> 3);       // tile row this lane stages
      int u  = lane & 7;                  // physical 16B unit within row
      int su = u ^ (mr & 7);              // source (logical) unit
      const unsigned short* srcA = A + (size_t)(trow0 + mr) * 1024 + kt * BKK + su * 8;
      gload_lds16(srcA, (char*)As + c * 1024);
      const unsigned short* srcB = Bt + (size_t)(ncol0 + mr) * 1024 + kt * BKK + su * 8;
      gload_lds16(srcB, (char*)Bs + c * 1024);
    }
    __syncthreads();

    bf16x8 af[4][2], bfr[4][2];
    #pragma unroll
    for (int mi = 0; mi < 4; ++mi){
      int row = wm * 64 + mi * 16 + (lane & 15);
      #pragma unroll
      for (int ks = 0; ks < 2; ++ks){
        int u = ((lane >> 4) + 4 * ks) ^ (row & 7);
        af[mi][ks] = *(const bf16x8*)((const char*)As + row * 128 + u * 16);
      }
    }
    #pragma unroll
    for (int ni = 0; ni < 4; ++ni){
      int row = wn * 64 + ni * 16 + (lane & 15);
      #pragma unroll
      for (int ks = 0; ks < 2; ++ks){
        int u = ((lane >> 4) + 4 * ks) ^ (row & 7);
        bfr[ni][ks] = *(const bf16x8*)((const char*)Bs + row * 128 + u * 16);
      }
    }
    #pragma unroll
    for (int mi = 0; mi < 4; ++mi)
      #pragma unroll
      for (int ni = 0; ni < 4; ++ni)
        #pragma unroll
        for (int ks = 0; ks < 2; ++ks)
          acc[mi][ni] = __builtin_amdgcn_mfma_f32_16x16x32_bf16(
              af[mi][ks], bfr[ni][ks], acc[mi][ni], 0, 0, 0);
  }

  #pragma unroll
  for (int mi = 0; mi < 4; ++mi)
    #pragma unroll
    for (int ni = 0; ni < 4; ++ni){
      int col = ncol0 + wn * 64 + ni * 16 + (lane & 15);
      #pragma unroll
      for (int reg = 0; reg < 4; ++reg){
        int row = trow0 + wm * 64 + mi * 16 + (lane >> 4) * 4 + reg;
        C[(size_t)row * 1024 + col] = f2bf(acc[mi][ni][reg]);
      }
    }
}

// ---------------- depthwise causal conv via v_dot2_f32_bf16 ----------------
// out[m0+m] = sum_{r<=m0+m} pe[r]*y[m0+m-r] per (b,p,d) column.
// Chunks of 16 taps, r0 = m0, m0-16, ..., 0 (j0 = m0-r0 ascending).
// Packed window W[idx] = (lo=y[j0-14+idx], hi=y[j0-15+idx]), 30 entries.
// acc[m] += dot2(pv[q], W[m+14-2q]), q=0..7  -> 128 dot2 / chunk.
#define MV 16
__device__ __forceinline__ void conv_tile16(const unsigned short* __restrict__ ycol,
                                            const unsigned int* __restrict__ pcol,
                                            float* __restrict__ ocol, int m0){
  float acc[MV];
  #pragma unroll
  for (int m = 0; m < MV; ++m) acc[m] = 0.f;

  unsigned int W[30];
  #pragma unroll
  for (int t = 0; t < 14; ++t) W[t] = 0u;
  {
    unsigned int y0 = ycol[0];
    W[14] = y0;                              // (y[0], y[-1]=0)
    unsigned int prev = y0;
    #pragma unroll
    for (int t = 1; t < 16; ++t){
      unsigned int yt = ycol[(size_t)t * 2048];
      W[14 + t] = yt | (prev << 16);
      prev = yt;
    }
  }
  unsigned int prev15 = ycol[(size_t)15 * 2048];  // y[j0+15] carried across chunks

  unsigned int pv[8];
  #pragma unroll
  for (int q = 0; q < 8; ++q) pv[q] = pcol[(size_t)((m0 >> 1) + q) * 1024];

  int nch = (m0 >> 4) + 1;
  for (int c = 0; c + 1 < nch; ++c){
    int j0 = 16 * c;
    int r0 = m0 - 16 * c;
    // prefetch next chunk: y[j0+16 .. j0+31], pepk rows (r0-16)/2 ..
    unsigned int ny[16], npv[8];
    #pragma unroll
    for (int t = 0; t < 16; ++t) ny[t] = ycol[(size_t)(j0 + 16 + t) * 2048];
    #pragma unroll
    for (int q = 0; q < 8; ++q) npv[q] = pcol[(size_t)(((r0 - 16) >> 1) + q) * 1024];

    #pragma unroll
    for (int q = 0; q < 8; ++q)
      #pragma unroll
      for (int m = 0; m < MV; ++m)
        acc[m] = dot2bf(pv[q], W[m + 14 - 2 * q], acc[m]);

    // slide window by 16
    #pragma unroll
    for (int t = 0; t < 14; ++t) W[t] = W[t + 16];
    W[14] = ny[0] | (prev15 << 16);
    #pragma unroll
    for (int t = 1; t < 16; ++t) W[14 + t] = ny[t] | (ny[t - 1] << 16);
    prev15 = ny[15];
    #pragma unroll
    for (int q = 0; q < 8; ++q) pv[q] = npv[q];
  }
  // last chunk (r0 == 0)
  #pragma unroll
  for (int q = 0; q < 8; ++q)
    #pragma unroll
    for (int m = 0; m < MV; ++m)
      acc[m] = dot2bf(pv[q], W[m + 14 - 2 * q], acc[m]);

  #pragma unroll
  for (int m = 0; m < MV; ++m)
    ocol[(size_t)(m0 + m) * 2048] = acc[m];
}

__global__ __launch_bounds__(256, 4)
void k_conv(const unsigned short* __restrict__ xp,   // [8192][1024] bf16
            const unsigned int* __restrict__ pepk,   // [512][1024] packed pe pairs
            float* __restrict__ out){                // [4][2048][1024] f32
  int d    = blockIdx.x * 256 + threadIdx.x;  // 0..1023
  int pair = blockIdx.y;                      // 0..31 -> tiles {pair, 63-pair}
  int bp   = blockIdx.z;                      // 0..7
  int b = bp >> 1, p = bp & 1;
  const unsigned short* ycol = xp + (size_t)(b * SEQ + p) * DIM + d;
  const unsigned int*   pcol = pepk + d;
  float* ocol = out + (size_t)(b * SEQ + p) * DIM + d;

  conv_tile16(ycol, pcol, ocol, pair * MV);          // small tile
  conv_tile16(ycol, pcol, ocol, (63 - pair) * MV);   // large tile (65 chunks total)
}

extern "C" void kernel_launch(void* const* d_in, const int* in_sizes, int n_in,
                              void* d_out, int out_size, void* d_ws, size_t ws_size,
                              hipStream_t stream){
  const float* x       = (const float*)d_in[0];
  const float* filters = (const float*)d_in[1];
  const float* Mi      = (const float*)d_in[2];
  const float* Mf      = (const float*)d_in[3];

  char* ws = (char*)d_ws;
  unsigned short* Xb   = (unsigned short*)(ws);                              // 16 MB
  unsigned short* XPb  = (unsigned short*)(ws + (size_t)16 * 1024 * 1024);   // 16 MB
  unsigned short* MbT  = (unsigned short*)(ws + (size_t)32 * 1024 * 1024);   //  2 MB
  unsigned int*   pepk = (unsigned int*)  (ws + (size_t)34 * 1024 * 1024);   //  2 MB
  float* out = (float*)d_out;

  hipLaunchKernelGGL(k_cvt_x, dim3(8192), dim3(256), 0, stream, x, Xb);
  hipLaunchKernelGGL(k_tr_M,  dim3(32, 32), dim3(32, 8), 0, stream, Mi, MbT);
  hipLaunchKernelGGL(k_pe,    dim3(4, 512), dim3(256), 0, stream, filters, Mf, pepk);
  hipLaunchKernelGGL(k_gemm,  dim3(64, 8), dim3(256), 0, stream, Xb, MbT, XPb);
  hipLaunchKernelGGL(k_conv,  dim3(4, 32, 8), dim3(256), 0, stream, XPb, pepk, out);
}